// Round 2
// baseline (126.954 us; speedup 1.0000x reference)
//
#include <hip/hip_runtime.h>

#define NROWS 8192
#define KDIM  512
#define NT    64                 // 8192/128 tiles per dim
#define NBLK  (NT*(NT+1)/2)      // upper-triangle tile pairs = 2080
#define SCL1  0x7F7F7F7F         // E8M0 scale bytes = 2^0 = 1.0
#define STRIP4 8192              // 32 rows x 512 k x 0.5 B per strip
#define C2    0.0144269504f      // log2(e)/100

typedef __attribute__((ext_vector_type(16))) float f32x16;
typedef __attribute__((ext_vector_type(4))) int i32x4;
typedef __attribute__((ext_vector_type(8))) int i32x8;

__device__ __forceinline__ i32x8 mk_op4(i32x4 lo) {
    i32x8 r;
    r[0] = lo[0]; r[1] = lo[1]; r[2] = lo[2]; r[3] = lo[3];
    r[4] = 0; r[5] = 0; r[6] = 0; r[7] = 0;   // fp4 uses only first 4 dwords
    return r;
}

// nearest e2m1 (scale 1.0) code for |x|: {0,0.5,1,1.5,2,3,4,6}
__device__ __forceinline__ int fp4_code(float x) {
    float v = fabsf(x);
    int c = v < 0.25f ? 0 : v < 0.75f ? 1 : v < 1.25f ? 2 : v < 1.75f ? 3
          : v < 2.5f  ? 4 : v < 3.5f  ? 5 : v < 5.0f  ? 6 : 7;
    return c | (x < 0.f ? 8 : 0);
}

// z (fp32) -> fp4 e2m1 in MFMA-operand order (bitwise identical zb4/nq to prior
// rounds). Also zeroes the gram completion counter (workspace re-poisoned every
// iteration, so cnt must be cleared here).
__global__ __launch_bounds__(256) void prep_kernel(const float* __restrict__ z,
                                                   unsigned char* __restrict__ zb4,
                                                   float* __restrict__ nq,
                                                   int* __restrict__ cnt) {
    if (blockIdx.x == 0 && threadIdx.x == 0) *cnt = 0;
    int wave = threadIdx.x >> 6, lane = threadIdx.x & 63;
    int row = blockIdx.x * 4 + wave;
    const float* zr = z + (size_t)row * KDIM + lane * 8;
    float4 v0 = *(const float4*)zr;
    float4 v1 = *(const float4*)(zr + 4);
    float vals[8] = {v0.x, v0.y, v0.z, v0.w, v1.x, v1.y, v1.z, v1.w};
    float s = 0.f;
    unsigned int pk = 0u;
#pragma unroll
    for (int i = 0; i < 8; ++i) {
        s += vals[i] * vals[i];
        pk |= (unsigned int)fp4_code(vals[i]) << (4 * i);   // nibble i = k0+i
    }
    int strip = row >> 5, lr = row & 31;
    size_t addr = (size_t)strip * STRIP4 + (lane >> 3) * 1024 +
                  ((lane >> 2) & 1) * 512 + lr * 16 + (lane & 3) * 4;
    *(unsigned int*)(zb4 + addr) = pk;
#pragma unroll
    for (int off = 32; off; off >>= 1) s += __shfl_down(s, off);
    if (lane == 0) nq[row] = -C2 * s;
}

// 128x128 Gram tile per block, 64x64 per wave (2x2 32x32x64 MX-fp4 MFMA).
// REVERTED to direct-from-L2 operand loads (round-1's LDS staging serialized
// each block on a vmcnt(0) drain at 2 blocks/CU -> 68 us, MfmaUtil 4.7%).
// NEW vs round 0: __launch_bounds__(256,4) -> 4 blocks/CU (16 waves/CU, was
// 12). Kernel needs ~88 VGPR so the <=128 VGPR budget holds without spills;
// the extra resident waves deepen memory-level parallelism on the L2-latency-
// bound load stream. No LDS staging, no barriers in the main loop.
// Fused last-block final reduction (deterministic, replicates the old
// reduce_kernel summation order exactly) kept from round 1.
__global__ __launch_bounds__(256, 4) void gram_kernel(const unsigned char* __restrict__ zb4,
                                                      const float* __restrict__ nq,
                                                      float* __restrict__ part,
                                                      int* __restrict__ cnt,
                                                      float* __restrict__ out) {
    __shared__ float wsum[4];
    __shared__ int lastFlag;

    int tid = threadIdx.x;
    int wave = tid >> 6, lane = tid & 63;
    int ln31 = lane & 31, kh = lane >> 5;
    int wm = wave >> 1, wn = wave & 1;

    // linear block id -> (bi, bj), bi <= bj
    int rem = blockIdx.x, bi = 0;
    while (rem >= NT - bi) { rem -= NT - bi; ++bi; }
    int bj = bi + rem;
    int rot = blockIdx.x & 7;

    int laneOff = kh * 512 + ln31 * 16;
    const unsigned char* pA0 = zb4 + (size_t)(bi * 4 + wm * 2) * STRIP4 + laneOff;
    const unsigned char* pA1 = pA0 + STRIP4;
    const unsigned char* pB0 = zb4 + (size_t)(bj * 4 + wn * 2) * STRIP4 + laneOff;
    const unsigned char* pB1 = pB0 + STRIP4;

    f32x16 accf[2][2];
#pragma unroll
    for (int mi = 0; mi < 2; ++mi)
#pragma unroll
        for (int ni = 0; ni < 2; ++ni)
#pragma unroll
            for (int r = 0; r < 16; ++r) accf[mi][ni][r] = 0.f;

#pragma unroll
    for (int ks = 0; ks < 8; ++ks) {
        int off = ((ks + rot) & 7) * 1024;   // rotated k-slice (same fp32 acc order)
        i32x8 a0 = mk_op4(*(const i32x4*)(pA0 + off));
        i32x8 a1 = mk_op4(*(const i32x4*)(pA1 + off));
        i32x8 b0 = mk_op4(*(const i32x4*)(pB0 + off));
        i32x8 b1 = mk_op4(*(const i32x4*)(pB1 + off));
        // cbsz=4 (A=fp4), blgp=4 (B=fp4), scales = 1.0
        accf[0][0] = __builtin_amdgcn_mfma_scale_f32_32x32x64_f8f6f4(a0, b0, accf[0][0], 4, 4, 0, SCL1, 0, SCL1);
        accf[0][1] = __builtin_amdgcn_mfma_scale_f32_32x32x64_f8f6f4(a0, b1, accf[0][1], 4, 4, 0, SCL1, 0, SCL1);
        accf[1][0] = __builtin_amdgcn_mfma_scale_f32_32x32x64_f8f6f4(a1, b0, accf[1][0], 4, 4, 0, SCL1, 0, SCL1);
        accf[1][1] = __builtin_amdgcn_mfma_scale_f32_32x32x64_f8f6f4(a1, b1, accf[1][1], 4, 4, 0, SCL1, 0, SCL1);
    }

    // ---- fused epilogue: exp2( min( s*2C2 + nq_i + nq_j, 0 ) ) ----
    int rowBase = bi * 128 + wm * 64;
    int colBase = bj * 128 + wn * 64;
    float nqj[2] = { nq[colBase + ln31], nq[colBase + 32 + ln31] };

    float local = 0.f;
    if (bi != bj) {
#pragma unroll
        for (int mi = 0; mi < 2; ++mi) {
#pragma unroll
            for (int reg = 0; reg < 16; ++reg) {
                int rowf = (reg & 3) + 8 * (reg >> 2) + 4 * kh;
                float nqi = nq[rowBase + mi * 32 + rowf];
#pragma unroll
                for (int ni = 0; ni < 2; ++ni) {
                    float arg = fmaf(accf[mi][ni][reg], 2.f * C2, nqi + nqj[ni]);
                    local += __builtin_exp2f(fminf(arg, 0.f));
                }
            }
        }
    } else {
#pragma unroll
        for (int mi = 0; mi < 2; ++mi) {
#pragma unroll
            for (int reg = 0; reg < 16; ++reg) {
                int rowf = (reg & 3) + 8 * (reg >> 2) + 4 * kh;
                int gi = rowBase + mi * 32 + rowf;
                float nqi = nq[gi];
#pragma unroll
                for (int ni = 0; ni < 2; ++ni) {
                    int gj = colBase + ni * 32 + ln31;
                    float arg = fmaf(accf[mi][ni][reg], 2.f * C2, nqi + nqj[ni]);
                    float e = __builtin_exp2f(fminf(arg, 0.f));
                    local += (gi < gj) ? e : 0.f;
                }
            }
        }
    }

#pragma unroll
    for (int off = 32; off; off >>= 1) local += __shfl_down(local, off);
    if (lane == 0) wsum[wave] = local;
    __syncthreads();

    // ---- publish partial + deterministic last-block final reduction ----
    if (tid == 0) {
        float val = wsum[0] + wsum[1] + wsum[2] + wsum[3];
        __hip_atomic_store(&part[blockIdx.x], val, __ATOMIC_RELEASE,
                           __HIP_MEMORY_SCOPE_AGENT);
        int old = __hip_atomic_fetch_add(cnt, 1, __ATOMIC_ACQ_REL,
                                         __HIP_MEMORY_SCOPE_AGENT);
        lastFlag = (old == NBLK - 1);
    }
    __syncthreads();

    if (lastFlag) {   // uniform across block; replicates old reduce_kernel exactly
        float s = 0.f;
        for (int i = tid; i < NBLK; i += 256)
            s += __hip_atomic_load(&part[i], __ATOMIC_RELAXED,
                                   __HIP_MEMORY_SCOPE_AGENT);
#pragma unroll
        for (int off = 32; off; off >>= 1) s += __shfl_down(s, off);
        if (lane == 0) wsum[wave] = s;
        __syncthreads();
        if (tid == 0) {
            float total = 2.f * (wsum[0] + wsum[1] + wsum[2] + wsum[3]);
            out[0] = logf(total / ((float)NROWS * (float)(NROWS - 1)));
        }
    }
}

extern "C" void kernel_launch(void* const* d_in, const int* in_sizes, int n_in,
                              void* d_out, int out_size, void* d_ws, size_t ws_size,
                              hipStream_t stream) {
    const float* z = (const float*)d_in[0];
    float* out = (float*)d_out;
    unsigned char* zb4 = (unsigned char*)d_ws;                    // 2 MB fp4, operand order
    float* nq = (float*)((char*)d_ws + (size_t)NROWS * KDIM / 2); // 32 KB
    float* part = nq + NROWS;                                     // 2080 floats
    int* cnt = (int*)(part + NBLK);                               // completion counter

    prep_kernel<<<NROWS / 4, 256, 0, stream>>>(z, zb4, nq, cnt);
    gram_kernel<<<NBLK, 256, 0, stream>>>(zb4, nq, part, cnt, out);
}

// Round 4
// 105.407 us; speedup vs baseline: 1.2044x; 1.2044x over previous
//
#include <hip/hip_runtime.h>

#define NROWS 8192
#define KDIM  512
#define NT    64                 // 8192/128 tiles per dim
#define NBLK  (NT*(NT+1)/2)      // upper-triangle tile pairs = 2080
#define SCL1  0x7F7F7F7F         // E8M0 scale bytes = 2^0 = 1.0
#define STRIP4 8192              // 32 rows x 512 k x 0.5 B per strip
#define C2    0.0144269504f      // log2(e)/100

typedef __attribute__((ext_vector_type(16))) float f32x16;
typedef __attribute__((ext_vector_type(4))) int i32x4;
typedef __attribute__((ext_vector_type(8))) int i32x8;

__device__ __forceinline__ i32x8 mk_op4(i32x4 lo) {
    i32x8 r;
    r[0] = lo[0]; r[1] = lo[1]; r[2] = lo[2]; r[3] = lo[3];
    r[4] = 0; r[5] = 0; r[6] = 0; r[7] = 0;   // fp4 uses only first 4 dwords
    return r;
}

// nearest e2m1 (scale 1.0) code for |x|: {0,0.5,1,1.5,2,3,4,6}
__device__ __forceinline__ int fp4_code(float x) {
    float v = fabsf(x);
    int c = v < 0.25f ? 0 : v < 0.75f ? 1 : v < 1.25f ? 2 : v < 1.75f ? 3
          : v < 2.5f  ? 4 : v < 3.5f  ? 5 : v < 5.0f  ? 6 : 7;
    return c | (x < 0.f ? 8 : 0);
}

// z (fp32) -> fp4 e2m1 in MFMA-operand order (bitwise identical zb4/nq to prior
// rounds). Also zeroes the gram completion counter (workspace re-poisoned every
// iteration, so cnt must be cleared here).
__global__ __launch_bounds__(256) void prep_kernel(const float* __restrict__ z,
                                                   unsigned char* __restrict__ zb4,
                                                   float* __restrict__ nq,
                                                   int* __restrict__ cnt) {
    if (blockIdx.x == 0 && threadIdx.x == 0) *cnt = 0;
    int wave = threadIdx.x >> 6, lane = threadIdx.x & 63;
    int row = blockIdx.x * 4 + wave;
    const float* zr = z + (size_t)row * KDIM + lane * 8;
    float4 v0 = *(const float4*)zr;
    float4 v1 = *(const float4*)(zr + 4);
    float vals[8] = {v0.x, v0.y, v0.z, v0.w, v1.x, v1.y, v1.z, v1.w};
    float s = 0.f;
    unsigned int pk = 0u;
#pragma unroll
    for (int i = 0; i < 8; ++i) {
        s += vals[i] * vals[i];
        pk |= (unsigned int)fp4_code(vals[i]) << (4 * i);   // nibble i = k0+i
    }
    int strip = row >> 5, lr = row & 31;
    size_t addr = (size_t)strip * STRIP4 + (lane >> 3) * 1024 +
                  ((lane >> 2) & 1) * 512 + lr * 16 + (lane & 3) * 4;
    *(unsigned int*)(zb4 + addr) = pk;
#pragma unroll
    for (int off = 32; off; off >>= 1) s += __shfl_down(s, off);
    if (lane == 0) nq[row] = -C2 * s;
}

// 128x128 Gram tile per block, 64x64 per wave (2x2 32x32x64 MX-fp4 MFMA).
// Direct-from-L2 operand loads, launch_bounds(256,3) — the round-0 proven
// codegen (~30 us). Fused last-block reduction KEPT but with fixed memory
// ordering: rounds 1-2 used an agent-scope ACQ_REL fetch_add per block, whose
// acquire half compiles to a full per-XCD L2 invalidate. 2080 invalidates
// (~1 per 260 ns per XCD) kept zb4 from ever staying L2-resident -> every
// block re-read its 128 KB of operands from L3 on the latency-critical path
// -> 68 us regardless of occupancy (rounds 1 AND 2 identical at 68 despite
// different structures). Fix: per-block RELEASE-only RMW (L2 writeback —
// flushes the ~1 dirty line, PRESERVES clean zb4 lines); the single last
// block performs the only acquire (one L2 invalidate in the whole grid).
__global__ __launch_bounds__(256, 3) void gram_kernel(const unsigned char* __restrict__ zb4,
                                                      const float* __restrict__ nq,
                                                      float* __restrict__ part,
                                                      int* __restrict__ cnt,
                                                      float* __restrict__ out) {
    __shared__ float wsum[4];
    __shared__ int lastFlag;

    int tid = threadIdx.x;
    int wave = tid >> 6, lane = tid & 63;
    int ln31 = lane & 31, kh = lane >> 5;
    int wm = wave >> 1, wn = wave & 1;

    // linear block id -> (bi, bj), bi <= bj
    int rem = blockIdx.x, bi = 0;
    while (rem >= NT - bi) { rem -= NT - bi; ++bi; }
    int bj = bi + rem;
    int rot = blockIdx.x & 7;

    int laneOff = kh * 512 + ln31 * 16;
    const unsigned char* pA0 = zb4 + (size_t)(bi * 4 + wm * 2) * STRIP4 + laneOff;
    const unsigned char* pA1 = pA0 + STRIP4;
    const unsigned char* pB0 = zb4 + (size_t)(bj * 4 + wn * 2) * STRIP4 + laneOff;
    const unsigned char* pB1 = pB0 + STRIP4;

    f32x16 accf[2][2];
#pragma unroll
    for (int mi = 0; mi < 2; ++mi)
#pragma unroll
        for (int ni = 0; ni < 2; ++ni)
#pragma unroll
            for (int r = 0; r < 16; ++r) accf[mi][ni][r] = 0.f;

#pragma unroll
    for (int ks = 0; ks < 8; ++ks) {
        int off = ((ks + rot) & 7) * 1024;   // rotated k-slice (same fp32 acc order)
        i32x8 a0 = mk_op4(*(const i32x4*)(pA0 + off));
        i32x8 a1 = mk_op4(*(const i32x4*)(pA1 + off));
        i32x8 b0 = mk_op4(*(const i32x4*)(pB0 + off));
        i32x8 b1 = mk_op4(*(const i32x4*)(pB1 + off));
        // cbsz=4 (A=fp4), blgp=4 (B=fp4), scales = 1.0
        accf[0][0] = __builtin_amdgcn_mfma_scale_f32_32x32x64_f8f6f4(a0, b0, accf[0][0], 4, 4, 0, SCL1, 0, SCL1);
        accf[0][1] = __builtin_amdgcn_mfma_scale_f32_32x32x64_f8f6f4(a0, b1, accf[0][1], 4, 4, 0, SCL1, 0, SCL1);
        accf[1][0] = __builtin_amdgcn_mfma_scale_f32_32x32x64_f8f6f4(a1, b0, accf[1][0], 4, 4, 0, SCL1, 0, SCL1);
        accf[1][1] = __builtin_amdgcn_mfma_scale_f32_32x32x64_f8f6f4(a1, b1, accf[1][1], 4, 4, 0, SCL1, 0, SCL1);
    }

    // ---- fused epilogue: exp2( min( s*2C2 + nq_i + nq_j, 0 ) ) ----
    int rowBase = bi * 128 + wm * 64;
    int colBase = bj * 128 + wn * 64;
    float nqj[2] = { nq[colBase + ln31], nq[colBase + 32 + ln31] };

    float local = 0.f;
    if (bi != bj) {
#pragma unroll
        for (int mi = 0; mi < 2; ++mi) {
#pragma unroll
            for (int reg = 0; reg < 16; ++reg) {
                int rowf = (reg & 3) + 8 * (reg >> 2) + 4 * kh;
                float nqi = nq[rowBase + mi * 32 + rowf];
#pragma unroll
                for (int ni = 0; ni < 2; ++ni) {
                    float arg = fmaf(accf[mi][ni][reg], 2.f * C2, nqi + nqj[ni]);
                    local += __builtin_exp2f(fminf(arg, 0.f));
                }
            }
        }
    } else {
#pragma unroll
        for (int mi = 0; mi < 2; ++mi) {
#pragma unroll
            for (int reg = 0; reg < 16; ++reg) {
                int rowf = (reg & 3) + 8 * (reg >> 2) + 4 * kh;
                int gi = rowBase + mi * 32 + rowf;
                float nqi = nq[gi];
#pragma unroll
                for (int ni = 0; ni < 2; ++ni) {
                    int gj = colBase + ni * 32 + ln31;
                    float arg = fmaf(accf[mi][ni][reg], 2.f * C2, nqi + nqj[ni]);
                    float e = __builtin_exp2f(fminf(arg, 0.f));
                    local += (gi < gj) ? e : 0.f;
                }
            }
        }
    }

#pragma unroll
    for (int off = 32; off; off >>= 1) local += __shfl_down(local, off);
    if (lane == 0) wsum[wave] = local;
    __syncthreads();

    // ---- publish partial + deterministic last-block final reduction ----
    if (tid == 0) {
        float val = wsum[0] + wsum[1] + wsum[2] + wsum[3];
        __hip_atomic_store(&part[blockIdx.x], val, __ATOMIC_RELAXED,
                           __HIP_MEMORY_SCOPE_AGENT);
        // RELEASE orders the part store to the coherence point; writeback
        // only — clean L2 lines (zb4) stay resident. No per-block acquire.
        int old = __hip_atomic_fetch_add(cnt, 1, __ATOMIC_RELEASE,
                                         __HIP_MEMORY_SCOPE_AGENT);
        lastFlag = (old == NBLK - 1);
    }
    __syncthreads();

    if (lastFlag) {   // uniform across block; replicates old reduce_kernel exactly
        if (tid == 0)  // the ONLY acquire in the grid: one L2 invalidate, after
                       // all 2079 release-RMWs have published their partials
            (void)__hip_atomic_load(cnt, __ATOMIC_ACQUIRE, __HIP_MEMORY_SCOPE_AGENT);
        __syncthreads();
        float s = 0.f;
        for (int i = tid; i < NBLK; i += 256)
            s += __hip_atomic_load(&part[i], __ATOMIC_RELAXED,
                                   __HIP_MEMORY_SCOPE_AGENT);
#pragma unroll
        for (int off = 32; off; off >>= 1) s += __shfl_down(s, off);
        if (lane == 0) wsum[wave] = s;
        __syncthreads();
        if (tid == 0) {
            float total = 2.f * (wsum[0] + wsum[1] + wsum[2] + wsum[3]);
            out[0] = logf(total / ((float)NROWS * (float)(NROWS - 1)));
        }
    }
}

extern "C" void kernel_launch(void* const* d_in, const int* in_sizes, int n_in,
                              void* d_out, int out_size, void* d_ws, size_t ws_size,
                              hipStream_t stream) {
    const float* z = (const float*)d_in[0];
    float* out = (float*)d_out;
    unsigned char* zb4 = (unsigned char*)d_ws;                    // 2 MB fp4, operand order
    float* nq = (float*)((char*)d_ws + (size_t)NROWS * KDIM / 2); // 32 KB
    float* part = nq + NROWS;                                     // 2080 floats
    int* cnt = (int*)(part + NBLK);                               // completion counter

    prep_kernel<<<NROWS / 4, 256, 0, stream>>>(z, zb4, nq, cnt);
    gram_kernel<<<NBLK, 256, 0, stream>>>(zb4, nq, part, cnt, out);
}

// Round 5
// 84.926 us; speedup vs baseline: 1.4949x; 1.2412x over previous
//
#include <hip/hip_runtime.h>

#define NROWS 8192
#define KDIM  512
#define NT    64                 // 8192/128 tiles per dim
#define NBLK  (NT*(NT+1)/2)      // upper-triangle tile pairs = 2080
#define SCL1  0x7F7F7F7F         // E8M0 scale bytes = 2^0 = 1.0
#define STRIP4 8192              // 32 rows x 512 k x 0.5 B per strip
#define C2    0.0144269504f      // log2(e)/100

typedef __attribute__((ext_vector_type(16))) float f32x16;
typedef __attribute__((ext_vector_type(4))) int i32x4;
typedef __attribute__((ext_vector_type(8))) int i32x8;

__device__ __forceinline__ i32x8 mk_op4(i32x4 lo) {
    i32x8 r;
    r[0] = lo[0]; r[1] = lo[1]; r[2] = lo[2]; r[3] = lo[3];
    r[4] = 0; r[5] = 0; r[6] = 0; r[7] = 0;   // fp4 uses only first 4 dwords
    return r;
}

// nearest e2m1 (scale 1.0) code for |x|: {0,0.5,1,1.5,2,3,4,6}
__device__ __forceinline__ int fp4_code(float x) {
    float v = fabsf(x);
    int c = v < 0.25f ? 0 : v < 0.75f ? 1 : v < 1.25f ? 2 : v < 1.75f ? 3
          : v < 2.5f  ? 4 : v < 3.5f  ? 5 : v < 5.0f  ? 6 : 7;
    return c | (x < 0.f ? 8 : 0);
}

// z (fp32) -> fp4 e2m1 in MFMA-operand order (bitwise identical zb4/nq to all
// prior rounds). nq[i] = -log2e/100 * ||z_i||^2 (exact fp32).
__global__ __launch_bounds__(256) void prep_kernel(const float* __restrict__ z,
                                                   unsigned char* __restrict__ zb4,
                                                   float* __restrict__ nq) {
    int wave = threadIdx.x >> 6, lane = threadIdx.x & 63;
    int row = blockIdx.x * 4 + wave;
    const float* zr = z + (size_t)row * KDIM + lane * 8;
    float4 v0 = *(const float4*)zr;
    float4 v1 = *(const float4*)(zr + 4);
    float vals[8] = {v0.x, v0.y, v0.z, v0.w, v1.x, v1.y, v1.z, v1.w};
    float s = 0.f;
    unsigned int pk = 0u;
#pragma unroll
    for (int i = 0; i < 8; ++i) {
        s += vals[i] * vals[i];
        pk |= (unsigned int)fp4_code(vals[i]) << (4 * i);   // nibble i = k0+i
    }
    int strip = row >> 5, lr = row & 31;
    size_t addr = (size_t)strip * STRIP4 + (lane >> 3) * 1024 +
                  ((lane >> 2) & 1) * 512 + lr * 16 + (lane & 3) * 4;
    *(unsigned int*)(zb4 + addr) = pk;
#pragma unroll
    for (int off = 32; off; off >>= 1) s += __shfl_down(s, off);
    if (lane == 0) nq[row] = -C2 * s;
}

// 128x128 Gram tile per block, 64x64 per wave (2x2 32x32x64 MX-fp4 MFMA).
// Round-0 proven skeleton (direct-from-L2 loads, plain part store, separate
// reduce launch whose kernel boundary provides coherence for free — rounds
// 1-4 showed ANY per-block agent-scope fence costs 15-38 us in evicted/
// written-back L2 state, far more than one extra 2-4 us launch).
// Latency-bound fixes (all bitwise-neutral):
//  (1) k-steps grouped in pairs: 8 loads issued back-to-back, then 8 MFMAs
//      -> 2x memory-level parallelism per wave (VGPR 52 held only ~3 loads
//      in flight before). Per-accumulator MFMA order unchanged (ks, ks+1).
//  (2) epilogue nq values prefetched as 8 float4 + 2 scalars BEFORE the
//      k-loop -> ~34 dependent ~300-cy broadcast loads hidden under MFMA.
//  (3) closed-form bi/bj replaces the up-to-64-iteration scalar while loop
//      that delayed each block's first load.
__global__ __launch_bounds__(256, 3) void gram_kernel(const unsigned char* __restrict__ zb4,
                                                      const float* __restrict__ nq,
                                                      float* __restrict__ part) {
    __shared__ float wsum[4];

    int tid = threadIdx.x;
    int wave = tid >> 6, lane = tid & 63;
    int ln31 = lane & 31, kh = lane >> 5;
    int wm = wave >> 1, wn = wave & 1;

    // linear block id -> (bi, bj), bi <= bj : closed form + 1-step correction.
    // C(b) = b*NT - b*(b-1)/2 entries precede row b; solve C(b) <= x < C(b+1).
    int x = blockIdx.x;
    float sq = __builtin_sqrtf(16641.0f - 8.0f * (float)x);   // (2*NT+1)^2 = 16641
    int bi = (int)((129.0f - sq) * 0.5f);
    while ((bi + 1) * NT - ((bi + 1) * bi >> 1) <= x) ++bi;   // float slack fixup
    while (bi * NT - (bi * (bi - 1) >> 1) > x) --bi;
    int rem = x - (bi * NT - (bi * (bi - 1) >> 1));
    int bj = bi + rem;
    int rot = blockIdx.x & 7;

    int laneOff = kh * 512 + ln31 * 16;
    const unsigned char* pA0 = zb4 + (size_t)(bi * 4 + wm * 2) * STRIP4 + laneOff;
    const unsigned char* pA1 = pA0 + STRIP4;
    const unsigned char* pB0 = zb4 + (size_t)(bj * 4 + wn * 2) * STRIP4 + laneOff;
    const unsigned char* pB1 = pB0 + STRIP4;

    // ---- prefetch epilogue nq operands (independent of k-loop) ----
    int rowBase = bi * 128 + wm * 64;
    int colBase = bj * 128 + wn * 64;
    float nqj[2] = { nq[colBase + ln31], nq[colBase + 32 + ln31] };
    // rows needed by this lane: rowBase + mi*32 + 4*kh + 8*g + e, e=reg&3, g=reg>>2
    float4 nq4[2][4];
#pragma unroll
    for (int mi = 0; mi < 2; ++mi)
#pragma unroll
        for (int g = 0; g < 4; ++g)
            nq4[mi][g] = *(const float4*)(nq + rowBase + mi * 32 + 4 * kh + 8 * g);

    f32x16 accf[2][2];
#pragma unroll
    for (int mi = 0; mi < 2; ++mi)
#pragma unroll
        for (int ni = 0; ni < 2; ++ni)
#pragma unroll
            for (int r = 0; r < 16; ++r) accf[mi][ni][r] = 0.f;

#pragma unroll
    for (int kp = 0; kp < 4; ++kp) {
        int off0 = ((2 * kp + rot) & 7) * 1024;       // rotated k-slices
        int off1 = ((2 * kp + 1 + rot) & 7) * 1024;   // (same acc order as before)
        i32x8 a0 = mk_op4(*(const i32x4*)(pA0 + off0));
        i32x8 a1 = mk_op4(*(const i32x4*)(pA1 + off0));
        i32x8 b0 = mk_op4(*(const i32x4*)(pB0 + off0));
        i32x8 b1 = mk_op4(*(const i32x4*)(pB1 + off0));
        i32x8 c0 = mk_op4(*(const i32x4*)(pA0 + off1));
        i32x8 c1 = mk_op4(*(const i32x4*)(pA1 + off1));
        i32x8 d0 = mk_op4(*(const i32x4*)(pB0 + off1));
        i32x8 d1 = mk_op4(*(const i32x4*)(pB1 + off1));
        // cbsz=4 (A=fp4), blgp=4 (B=fp4), scales = 1.0
        accf[0][0] = __builtin_amdgcn_mfma_scale_f32_32x32x64_f8f6f4(a0, b0, accf[0][0], 4, 4, 0, SCL1, 0, SCL1);
        accf[0][1] = __builtin_amdgcn_mfma_scale_f32_32x32x64_f8f6f4(a0, b1, accf[0][1], 4, 4, 0, SCL1, 0, SCL1);
        accf[1][0] = __builtin_amdgcn_mfma_scale_f32_32x32x64_f8f6f4(a1, b0, accf[1][0], 4, 4, 0, SCL1, 0, SCL1);
        accf[1][1] = __builtin_amdgcn_mfma_scale_f32_32x32x64_f8f6f4(a1, b1, accf[1][1], 4, 4, 0, SCL1, 0, SCL1);
        accf[0][0] = __builtin_amdgcn_mfma_scale_f32_32x32x64_f8f6f4(c0, d0, accf[0][0], 4, 4, 0, SCL1, 0, SCL1);
        accf[0][1] = __builtin_amdgcn_mfma_scale_f32_32x32x64_f8f6f4(c0, d1, accf[0][1], 4, 4, 0, SCL1, 0, SCL1);
        accf[1][0] = __builtin_amdgcn_mfma_scale_f32_32x32x64_f8f6f4(c1, d0, accf[1][0], 4, 4, 0, SCL1, 0, SCL1);
        accf[1][1] = __builtin_amdgcn_mfma_scale_f32_32x32x64_f8f6f4(c1, d1, accf[1][1], 4, 4, 0, SCL1, 0, SCL1);
    }

    // ---- fused epilogue: exp2( min( s*2C2 + nq_i + nq_j, 0 ) ) ----
    float local = 0.f;
    if (bi != bj) {
#pragma unroll
        for (int mi = 0; mi < 2; ++mi) {
#pragma unroll
            for (int reg = 0; reg < 16; ++reg) {
                float nqi = ((const float*)&nq4[mi][reg >> 2])[reg & 3];
#pragma unroll
                for (int ni = 0; ni < 2; ++ni) {
                    float arg = fmaf(accf[mi][ni][reg], 2.f * C2, nqi + nqj[ni]);
                    local += __builtin_exp2f(fminf(arg, 0.f));
                }
            }
        }
    } else {
#pragma unroll
        for (int mi = 0; mi < 2; ++mi) {
#pragma unroll
            for (int reg = 0; reg < 16; ++reg) {
                int rowf = (reg & 3) + 8 * (reg >> 2) + 4 * kh;
                int gi = rowBase + mi * 32 + rowf;
                float nqi = ((const float*)&nq4[mi][reg >> 2])[reg & 3];
#pragma unroll
                for (int ni = 0; ni < 2; ++ni) {
                    int gj = colBase + ni * 32 + ln31;
                    float arg = fmaf(accf[mi][ni][reg], 2.f * C2, nqi + nqj[ni]);
                    float e = __builtin_exp2f(fminf(arg, 0.f));
                    local += (gi < gj) ? e : 0.f;
                }
            }
        }
    }

#pragma unroll
    for (int off = 32; off; off >>= 1) local += __shfl_down(local, off);
    if (lane == 0) wsum[wave] = local;
    __syncthreads();
    if (tid == 0) part[blockIdx.x] = wsum[0] + wsum[1] + wsum[2] + wsum[3];  // plain store
}

// Single small block: sum the 2080 partials, take the log. The kernel
// boundary before this launch is the only coherence fence in the pipeline.
__global__ __launch_bounds__(256) void reduce_kernel(const float* __restrict__ part,
                                                     float* __restrict__ out) {
    int tid = threadIdx.x;
    int wave = tid >> 6, lane = tid & 63;
    float s = 0.f;
    for (int i = tid; i < NBLK; i += 256) s += part[i];
#pragma unroll
    for (int off = 32; off; off >>= 1) s += __shfl_down(s, off);
    __shared__ float w[4];
    if (lane == 0) w[wave] = s;
    __syncthreads();
    if (tid == 0) {
        float total = 2.f * (w[0] + w[1] + w[2] + w[3]);
        out[0] = logf(total / ((float)NROWS * (float)(NROWS - 1)));
    }
}

extern "C" void kernel_launch(void* const* d_in, const int* in_sizes, int n_in,
                              void* d_out, int out_size, void* d_ws, size_t ws_size,
                              hipStream_t stream) {
    const float* z = (const float*)d_in[0];
    float* out = (float*)d_out;
    unsigned char* zb4 = (unsigned char*)d_ws;                    // 2 MB fp4, operand order
    float* nq = (float*)((char*)d_ws + (size_t)NROWS * KDIM / 2); // 32 KB
    float* part = nq + NROWS;                                     // 2080 floats

    prep_kernel<<<NROWS / 4, 256, 0, stream>>>(z, zb4, nq);
    gram_kernel<<<NBLK, 256, 0, stream>>>(zb4, nq, part);
    reduce_kernel<<<1, 256, 0, stream>>>(part, out);
}